// Round 9
// baseline (911.580 us; speedup 1.0000x reference)
//
#include <hip/hip_runtime.h>
#include <hip/hip_bf16.h>
#include <stdint.h>
#include <math.h>

#define T_TOKENS 16384
#define DIM      512
#define NEXP     8
#define HID      2048

typedef __attribute__((ext_vector_type(8))) __bf16 bf16x8;
typedef __attribute__((ext_vector_type(16))) float f32x16;

__device__ __forceinline__ f32x16 mfma32(bf16x8 a, bf16x8 b, f32x16 c) {
  return __builtin_amdgcn_mfma_f32_32x32x16_bf16(a, b, c, 0, 0, 0);
}

#define WAITLGKM0 asm volatile("s_waitcnt lgkmcnt(0)" ::: "memory")
#define SBAR      asm volatile("s_barrier" ::: "memory")

// ---- JAX threefry2x32, key = (0, 42) ----
__device__ __forceinline__ void threefry2x32(uint32_t k0, uint32_t k1,
                                             uint32_t x0, uint32_t x1,
                                             uint32_t* o0, uint32_t* o1) {
  uint32_t ks0 = k0, ks1 = k1, ks2 = k0 ^ k1 ^ 0x1BD11BDAu;
#define TF_ROT(v, d) (((v) << (d)) | ((v) >> (32 - (d))))
#define TF_ROUND(r) { x0 += x1; x1 = TF_ROT(x1, r); x1 ^= x0; }
  x0 += ks0; x1 += ks1;
  TF_ROUND(13) TF_ROUND(15) TF_ROUND(26) TF_ROUND(6)
  x0 += ks1; x1 += ks2 + 1u;
  TF_ROUND(17) TF_ROUND(29) TF_ROUND(16) TF_ROUND(24)
  x0 += ks2; x1 += ks0 + 2u;
  TF_ROUND(13) TF_ROUND(15) TF_ROUND(26) TF_ROUND(6)
  x0 += ks0; x1 += ks1 + 3u;
  TF_ROUND(17) TF_ROUND(29) TF_ROUND(16) TF_ROUND(24)
  x0 += ks1; x1 += ks2 + 4u;
  TF_ROUND(13) TF_ROUND(15) TF_ROUND(26) TF_ROUND(6)
  x0 += ks2; x1 += ks0 + 5u;
#undef TF_ROUND
#undef TF_ROT
  *o0 = x0; *o1 = x1;
}

// ---- XLA ErfInv32 (Giles polynomial) ----
__device__ __forceinline__ float erfinv_xla(float x) {
  float w = -log1pf(__fmul_rn(-x, x));
  float p;
  if (w < 5.0f) {
    w = __fadd_rn(w, -2.5f);
    p = 2.81022636e-08f;
    p = __fadd_rn(3.43273939e-07f, __fmul_rn(p, w));
    p = __fadd_rn(-3.5233877e-06f, __fmul_rn(p, w));
    p = __fadd_rn(-4.39150654e-06f, __fmul_rn(p, w));
    p = __fadd_rn(0.00021858087f, __fmul_rn(p, w));
    p = __fadd_rn(-0.00125372503f, __fmul_rn(p, w));
    p = __fadd_rn(-0.00417768164f, __fmul_rn(p, w));
    p = __fadd_rn(0.246640727f, __fmul_rn(p, w));
    p = __fadd_rn(1.50140941f, __fmul_rn(p, w));
  } else {
    w = __fadd_rn(sqrtf(w), -3.0f);
    p = -0.000200214257f;
    p = __fadd_rn(0.000100950558f, __fmul_rn(p, w));
    p = __fadd_rn(0.00134934322f, __fmul_rn(p, w));
    p = __fadd_rn(-0.00367342844f, __fmul_rn(p, w));
    p = __fadd_rn(0.00573950773f, __fmul_rn(p, w));
    p = __fadd_rn(-0.0076224613f, __fmul_rn(p, w));
    p = __fadd_rn(0.00943887047f, __fmul_rn(p, w));
    p = __fadd_rn(1.00167406f, __fmul_rn(p, w));
    p = __fadd_rn(2.83297682f, __fmul_rn(p, w));
  }
  return __fmul_rn(p, x);
}

__device__ __forceinline__ float jax_normal_at(uint32_t i) {
  uint32_t o0, o1;
  threefry2x32(0u, 42u, 0u, i, &o0, &o1);
  uint32_t bits = o0 ^ o1;
  float f = __fadd_rn(__uint_as_float((bits >> 9) | 0x3f800000u), -1.0f);
  const float lo = -0.99999994f;
  float u = fmaxf(lo, __fadd_rn(__fmul_rn(f, 2.0f), lo));
  return __fmul_rn(1.4142135623730951f, erfinv_xla(u));
}

// ============ Kernel 1: zero-out + weight pack + router (one dispatch) ======
__global__ __launch_bounds__(256) void prep_router(
    const float* __restrict__ x, const float* __restrict__ Wr, const float* __restrict__ br,
    const float* __restrict__ Wn, const float* __restrict__ bn,
    const float* __restrict__ W1, const float* __restrict__ W2,
    __bf16* __restrict__ W1p, __bf16* __restrict__ W2p,
    uint8_t* __restrict__ fillRow, uint32_t* __restrict__ ltok2,
    float* __restrict__ out) {
  __shared__ float Ls[64][68];
  __shared__ float WrS[4224], WnS[4224];   // 512*8 + 16*8 pad
  __shared__ int lhist[8];
  const int tid = threadIdx.x;
  const int blk = blockIdx.x;

  // ---- zero out: 2M float4 over 4096 blocks ----
  {
    float4 z = {0.f, 0.f, 0.f, 0.f};
    ((float4*)out)[blk * 512 + tid] = z;
    ((float4*)out)[blk * 512 + 256 + tid] = z;
  }

  // ---- transpose-pack tile: dst[e][nt][ko][lc][j] = src[e][ko*8+j][nt*32+lc]
  {
    const float* src; __bf16* dst; int R, C, e, rt, ct;
    if (blk < 2048) { e = blk >> 8; int rem = blk & 255; rt = rem >> 5; ct = rem & 31;
                      src = W1; dst = W1p; R = 512; C = 2048; }
    else            { int v2 = blk - 2048; e = v2 >> 8; int rem = v2 & 255; rt = rem >> 3; ct = rem & 7;
                      src = W2; dst = W2p; R = 2048; C = 512; }
    const float* sp = src + (size_t)e * R * C + (size_t)(rt * 64) * C + ct * 64;
    int row = tid >> 4, col = (tid & 15) * 4;
#pragma unroll
    for (int it = 0; it < 4; ++it)
      *(float4*)&Ls[it * 16 + row][col] = *(const float4*)(sp + (size_t)(it * 16 + row) * C + col);
    __syncthreads();
    int KO = R >> 3;
#pragma unroll
    for (int q = 0; q < 2; ++q) {
      int f = tid + q * 256;
      int lc = f & 31, kol = (f >> 5) & 7, ntl = f >> 8;
      bf16x8 vv;
#pragma unroll
      for (int j = 0; j < 8; ++j) vv[j] = (__bf16)Ls[kol * 8 + j][ntl * 32 + lc];
      size_t idx = ((size_t)(e * (C >> 5) + ct * 2 + ntl) * KO + rt * 8 + kol) * 256 + lc * 8;
      *(bf16x8*)(dst + idx) = vv;
    }
  }

  if (blk >= 256) return;

  // ---- router: this block's 64-token slice ----
#pragma unroll
  for (int i = 0; i < 4; ++i) {
    int i4 = tid + i * 256;                // float4 index 0..1023
    int d = i4 >> 1, eh = (i4 & 1) * 4;
    *(float4*)&WrS[d * 8 + (d >> 5) * 8 + eh] = ((const float4*)Wr)[i4];
    *(float4*)&WnS[d * 8 + (d >> 5) * 8 + eh] = ((const float4*)Wn)[i4];
  }
  if (tid < 8) lhist[tid] = 0;
  __syncthreads();

  const int w = tid >> 6, lane = tid & 63;
  const int tl = lane & 3, dq = lane >> 2;
  const int el = (lane >> 2) & 7;

  for (int p = 0; p < 4; ++p) {
    int t = blk * 64 + p * 16 + w * 4 + tl;

    const float* xp = x + (size_t)t * DIM + dq * 32;
    float xv[32];
#pragma unroll
    for (int i = 0; i < 8; ++i) {
      float4 f = *(const float4*)(xp + i * 4);
      xv[i * 4 + 0] = f.x; xv[i * 4 + 1] = f.y; xv[i * 4 + 2] = f.z; xv[i * 4 + 3] = f.w;
    }

    double accR[8], accN[8];
#pragma unroll
    for (int e2 = 0; e2 < 8; ++e2) { accR[e2] = 0.0; accN[e2] = 0.0; }
#pragma unroll
    for (int r = 0; r < 32; ++r) {
      int d = dq * 32 + r;
      const float* wr = &WrS[d * 8 + (d >> 5) * 8];
      const float* wn = &WnS[d * 8 + (d >> 5) * 8];
      double xd = (double)xv[r];
#pragma unroll
      for (int e2 = 0; e2 < 8; ++e2) {
        accR[e2] += xd * (double)wr[e2];
        accN[e2] += xd * (double)wn[e2];
      }
    }
#pragma unroll
    for (int m = 4; m <= 32; m <<= 1) {
#pragma unroll
      for (int e2 = 0; e2 < 8; ++e2) {
        accR[e2] += __shfl_xor(accR[e2], m);
        accN[e2] += __shfl_xor(accN[e2], m);
      }
    }

    double accRm = 0.0, accNm = 0.0;
#pragma unroll
    for (int e2 = 0; e2 < 8; ++e2) {
      double vR = __shfl(accR[e2], tl);
      double vN = __shfl(accN[e2], tl);
      if (e2 == el) { accRm = vR; accNm = vN; }
    }
    double noisy = -1.0e308;
    if (lane < 32) {
      double logit = accRm + (double)br[el];
      double nlin  = accNm + (double)bn[el];
      double noise = (double)jax_normal_at((uint32_t)t * 8u + (uint32_t)el);
      double sp = fmax(nlin, 0.0) + log1p(exp(-fabs(nlin)));
      noisy = logit + noise * sp;
    }
    double v[8];
#pragma unroll
    for (int e2 = 0; e2 < 8; ++e2) v[e2] = __shfl(noisy, tl + 4 * e2);

    if (lane < 4) {
      int i1 = 0; double v1 = v[0];
#pragma unroll
      for (int e2 = 1; e2 < 8; ++e2) if (v[e2] > v1) { v1 = v[e2]; i1 = e2; }
      int i2 = -1; double v2 = -1.0e308;
#pragma unroll
      for (int e2 = 0; e2 < 8; ++e2) if (e2 != i1 && v[e2] > v2) { v2 = v[e2]; i2 = e2; }
      double w2 = exp(v2 - v1);
      double s = 1.0 + w2;
      uint32_t q1 = (uint32_t)((1.0 / s) * 262143.0 + 0.5);
      uint32_t q2 = (uint32_t)((w2 / s) * 262143.0 + 0.5);
      int p1 = atomicAdd(&lhist[i1], 1);
      ltok2[(blk * 8 + i1) * 64 + p1] = (uint32_t)t | (q1 << 14);
      int p2 = atomicAdd(&lhist[i2], 1);
      ltok2[(blk * 8 + i2) * 64 + p2] = (uint32_t)t | (q2 << 14);
    }
  }
  __syncthreads();
  if (tid < 8) fillRow[blk * 8 + tid] = (uint8_t)lhist[tid];
}

// ============ Kernel 2: expert FFN, M=128 single-round ======================
// 256 blocks (1/CU), 8 waves. Weight stream HALVED vs M=64 (1 GB total).
// Weights: global->VGPR double-buffered, wave-disjoint.
// FIX vs R8: weight base pointers use lm*8 (NOT lane*8) so the k-octet is
// ks*2+hi exactly once; R8 double-counted hi for lanes 32-63 in both GEMMs.
__global__ __launch_bounds__(512, 2) void expert_mfma(
    const float* __restrict__ x,
    const __bf16* __restrict__ W1p, const float* __restrict__ b1,
    const __bf16* __restrict__ W2p, const float* __restrict__ b2,
    const uint8_t* __restrict__ fillRow, const uint32_t* __restrict__ ltok2,
    float* __restrict__ out) {
  const int e = blockIdx.x & 7;          // XCD-pinned expert
  const int tslot = blockIdx.x >> 3;     // 0..31

  __shared__ __bf16 Xs[128 * 64 * 8];    // 131072 B  [tok][ko^(tok&31)][j]
  __shared__ __bf16 Hs[128 * 16 * 8];    // 32768 B   [tok][koH^(tok&15)][j]
  // scan/toks/gates alias into Hs (dead until first H write)
  int*   scanS = (int*)Hs;               // [256]
  int*   toksT = (int*)Hs + 256;         // [128]
  float* gateT = (float*)((int*)Hs + 384); // [128]

  const int tid  = threadIdx.x;
  const int lane = tid & 63;
  const int w    = tid >> 6;
  const int hi   = lane >> 5;
  const int lm   = lane & 31;

  // cnt via per-lane partial + wave butterfly (no LDS needed)
  int cnt = 0;
#pragma unroll
  for (int j = 0; j < 4; ++j) cnt += (int)fillRow[(lane * 4 + j) * 8 + e];
#pragma unroll
  for (int m = 1; m < 64; m <<= 1) cnt += __shfl_xor(cnt, m);

  const __bf16* W1e = W1p + (size_t)e * (64 * 64 * 256);
  const __bf16* W2e = W2p + (size_t)e * (16 * 256 * 256);

  const float b2r0 = b2[e * DIM + w * 64 + lm];
  const float b2r1 = b2[e * DIM + w * 64 + 32 + lm];

  for (int tile = tslot; tile * 128 < cnt; tile += 32) {
    int start = tile * 128;
    int nrow = min(128, cnt - start);

    __syncthreads();                     // Hs free (prev tile fully done)

    // ---- scan of slice counts (recomputed per tile; Hs-aliased) ----
    if (tid < 256) scanS[tid] = (int)fillRow[tid * 8 + e];
    __syncthreads();
    for (int d2 = 1; d2 < 256; d2 <<= 1) {
      int a = 0;
      if (tid < 256 && tid >= d2) a = scanS[tid - d2];
      __syncthreads();
      if (tid < 256 && tid >= d2) scanS[tid] += a;
      __syncthreads();
    }

    // ---- materialize this tile's 128 toks/gates ----
    if (tid < 128) {
      int tk = 0; float g = 0.f;
      if (tid < nrow) {
        int rank = start + tid;
        int s = 0;
#pragma unroll
        for (int st = 128; st; st >>= 1) {
          int t2 = s + st;
          if (t2 < 256 && scanS[t2 - 1] <= rank) s = t2;
        }
        int ex = s ? scanS[s - 1] : 0;
        uint32_t en = ltok2[(s * 8 + e) * 64 + (rank - ex)];
        tk = (int)(en & 16383u);
        g = (float)(en >> 14) * (1.f / 262143.f);
      }
      toksT[tid] = tk; gateT[tid] = g;
    }
    __syncthreads();

    // snapshot for epilogue (Hs region gets overwritten by H)
    const int   t0 = toksT[lane], t1 = toksT[64 + lane];
    const float g0 = gateT[lane], g1 = gateT[64 + lane];

    // ---- stage X tile: fp32 global -> bf16 LDS (swizzled A-frag) ----
    {
      int tm = tid >> 2, q = tid & 3;
      bool valid = tm < nrow;
      const float* xp = x + (size_t)(valid ? toksT[tm] : toksT[0]) * DIM + q * 128;
#pragma unroll
      for (int s2 = 0; s2 < 16; ++s2) {
        bf16x8 v;
        if (valid) {
          float4 f0 = *(const float4*)(xp + s2 * 8);
          float4 f1 = *(const float4*)(xp + s2 * 8 + 4);
          v[0] = (__bf16)f0.x; v[1] = (__bf16)f0.y; v[2] = (__bf16)f0.z; v[3] = (__bf16)f0.w;
          v[4] = (__bf16)f1.x; v[5] = (__bf16)f1.y; v[6] = (__bf16)f1.z; v[7] = (__bf16)f1.w;
        } else {
#pragma unroll
          for (int j = 0; j < 8; ++j) v[j] = (__bf16)0.f;
        }
        int ko = q * 16 + s2;
        *(bf16x8*)&Xs[((size_t)tm * 64 + (ko ^ (tm & 31))) * 8] = v;
      }
    }
    __syncthreads();                     // Xs + toks consumed; Hs free for H

    f32x16 acc2[2][4];
#pragma unroll
    for (int t = 0; t < 2; ++t)
#pragma unroll
      for (int g = 0; g < 4; ++g)
#pragma unroll
        for (int r = 0; r < 16; ++r) acc2[t][g][r] = 0.f;

    for (int c = 0; c < 8; ++c) {
      // ---- GEMM1: wave's n-tile = c*8+w, K=512, all 128 tokens ----
      const __bf16* w1l = W1e + ((size_t)((c * 8 + w) * 64)) * 256 + lm * 8;
      f32x16 acc1[4];
#pragma unroll
      for (int g = 0; g < 4; ++g)
#pragma unroll
        for (int r = 0; r < 16; ++r) acc1[g][r] = 0.f;

      bf16x8 wcur = *(const bf16x8*)(w1l + (size_t)hi * 256);
#pragma unroll
      for (int ks = 0; ks < 32; ++ks) {
        bf16x8 wnxt;
        if (ks < 31) wnxt = *(const bf16x8*)(w1l + (size_t)((ks + 1) * 2 + hi) * 256);
        int swz = (ks * 2 + hi) ^ lm;
#pragma unroll
        for (int g = 0; g < 4; ++g) {
          bf16x8 a = *(const bf16x8*)&Xs[((size_t)(g * 32 + lm) * 64 + swz) * 8];
          acc1[g] = mfma32(a, wcur, acc1[g]);
        }
        wcur = wnxt;
      }

      // ---- bias + relu -> bf16 regs (retained across half phases) ----
      float bias = b1[e * HID + (c * 8 + w) * 32 + lm];
      __bf16 hreg[4][16];
#pragma unroll
      for (int g = 0; g < 4; ++g)
#pragma unroll
        for (int r = 0; r < 16; ++r)
          hreg[g][r] = (__bf16)fmaxf(acc1[g][r] + bias, 0.f);

      // ---- two half-chunk phases: write 128-hid half -> GEMM2 on it ----
#pragma unroll
      for (int half = 0; half < 2; ++half) {
        if ((w >> 2) == half) {
          int koB = (w & 3) * 4 + (lm >> 3);
#pragma unroll
          for (int g = 0; g < 4; ++g)
#pragma unroll
            for (int r = 0; r < 16; ++r) {
              int tok = (r & 3) + 8 * (r >> 2) + 4 * hi + 32 * g;
              Hs[((size_t)tok * 16 + (koB ^ (tok & 15))) * 8 + (lm & 7)] = hreg[g][r];
            }
        }
        WAITLGKM0; SBAR;                 // Hs half ready for all waves

        // GEMM2: k = this 128-hid half, wave owns d [w*64, w*64+64)
        const __bf16* w2l = W2e + ((size_t)((2 * w) * 256 + c * 32 + half * 16)) * 256 + lm * 8;
        bf16x8 c0 = *(const bf16x8*)(w2l + (size_t)hi * 256);
        bf16x8 c1 = *(const bf16x8*)(w2l + 65536 + (size_t)hi * 256);
#pragma unroll
        for (int ks2 = 0; ks2 < 8; ++ks2) {
          bf16x8 n0, n1;
          if (ks2 < 7) {
            n0 = *(const bf16x8*)(w2l + (size_t)((ks2 + 1) * 2 + hi) * 256);
            n1 = *(const bf16x8*)(w2l + 65536 + (size_t)((ks2 + 1) * 2 + hi) * 256);
          }
          int koH = ks2 * 2 + hi;
          int swzH = koH ^ (lm & 15);
#pragma unroll
          for (int g = 0; g < 4; ++g) {
            bf16x8 ha = *(const bf16x8*)&Hs[((size_t)(g * 32 + lm) * 16 + swzH) * 8];
            acc2[0][g] = mfma32(ha, c0, acc2[0][g]);
            acc2[1][g] = mfma32(ha, c1, acc2[1][g]);
          }
          c0 = n0; c1 = n1;
        }
        SBAR;                            // all reads done before half rewrite
      }
    }

    // ---- epilogue: gate-weighted atomic accumulate, d-coalesced ----
#pragma unroll
    for (int t = 0; t < 2; ++t) {
      int d = w * 64 + t * 32 + lm;
      float b2v = t ? b2r1 : b2r0;
#pragma unroll
      for (int g = 0; g < 4; ++g)
#pragma unroll
        for (int r = 0; r < 16; ++r) {
          int row = (r & 3) + 8 * (r >> 2) + 4 * hi + 32 * g;
          int   tokv = __shfl(g < 2 ? t0 : t1, row & 63);
          float gv   = __shfl(g < 2 ? g0 : g1, row & 63);
          atomicAdd(out + (size_t)tokv * DIM + d, gv * (acc2[t][g][r] + b2v));
        }
    }
  }
}

extern "C" void kernel_launch(void* const* d_in, const int* in_sizes, int n_in,
                              void* d_out, int out_size, void* d_ws, size_t ws_size,
                              hipStream_t stream) {
  const float* x  = (const float*)d_in[0];
  const float* Wr = (const float*)d_in[1];
  const float* br = (const float*)d_in[2];
  const float* Wn = (const float*)d_in[3];
  const float* bn = (const float*)d_in[4];
  const float* W1 = (const float*)d_in[5];
  const float* b1 = (const float*)d_in[6];
  const float* W2 = (const float*)d_in[7];
  const float* b2 = (const float*)d_in[8];
  float* out = (float*)d_out;

  uint8_t* wsb = (uint8_t*)d_ws;
  uint8_t*  fillRow = wsb;                            // 256*8 u8 = 2048 B
  uint32_t* ltok2   = (uint32_t*)(wsb + 2048);        // 256*8*64*4 = 524288 B
  __bf16*   W1p     = (__bf16*)(wsb + 526336);        // 16 MB
  __bf16*   W2p     = (__bf16*)(wsb + 526336 + 16777216); // 16 MB
  // total ws usage: 526336 + 2*16777216 = 34,080,768 B (same as R7)

  prep_router<<<4096, 256, 0, stream>>>(x, Wr, br, Wn, bn, W1, W2, W1p, W2p,
                                        fillRow, ltok2, out);
  expert_mfma<<<256, 512, 0, stream>>>(x, W1p, b1, W2p, b2, fillRow, ltok2, out);
}